// Round 11
// baseline (155.116 us; speedup 1.0000x reference)
//
#include <hip/hip_runtime.h>
#include <hip/hip_bf16.h>

#define NROWS 16384
#define DDIM  256
#define LOG2E 1.44269504088896f

typedef __attribute__((ext_vector_type(8))) short bh8;    // 8 x bf16 (4 VGPR)
typedef __attribute__((ext_vector_type(4))) short bh4;
typedef __attribute__((ext_vector_type(4))) float fx4;
typedef __attribute__((ext_vector_type(16))) float fx16;  // 32x32 accumulator

__device__ __forceinline__ short f2bf(float x) {
  __hip_bfloat16 h = __float2bfloat16(x);
  return *reinterpret_cast<short*>(&h);
}

__device__ __forceinline__ float fexp2(float x) {
#if __has_builtin(__builtin_amdgcn_exp2f)
  return __builtin_amdgcn_exp2f(x);   // v_exp_f32: D = 2^S0
#else
  return __expf(x * 0.6931471805599453f);
#endif
}

__device__ __forceinline__ fx16 fzero16() {
  fx16 z;
#pragma unroll
  for (int q = 0; q < 16; ++q) z[q] = 0.f;
  return z;
}

// exact softplus, used only on the 16384 diagonal elements
__device__ __forceinline__ float softplus_f(float y) {
  float a = fabsf(y);
  float t = __expf(-a);
  float l;
  if (t < 0.125f) {
    l = t * (1.0f - t * (0.5f - 0.333333333f * t));
  } else {
    l = log1pf(t);
  }
  return fmaxf(y, 0.0f) + l;
}

__global__ void cast_bf16_kernel(const float* __restrict__ in,
                                 unsigned short* __restrict__ out) {
  int i = (blockIdx.x * blockDim.x + threadIdx.x) * 8;
  float4 v0 = *(const float4*)(in + i);
  float4 v1 = *(const float4*)(in + i + 4);
  bh8 o;
  o[0] = f2bf(v0.x); o[1] = f2bf(v0.y); o[2] = f2bf(v0.z); o[3] = f2bf(v0.w);
  o[4] = f2bf(v1.x); o[5] = f2bf(v1.y); o[6] = f2bf(v1.z); o[7] = f2bf(v1.w);
  *(bh8*)((unsigned short*)out + i) = o;
}

// ============ persistent strip kernel: A-in-reg + B-frag reg dbuf =========
// 512 blocks (2/CU), 256 threads = 4 waves (2 wr x 2 wc), wave tile 64x64 of
// mfma_f32_32x32x16_bf16 (2x2 fx16). Block = 128 img rows x 4096 txt cols.
// A resident in 128 regs/wave. B ring 4 x 16KB LDS; chunk = 128 cols x K=64.
// R10->R11: B fragments double-buffered in REGISTERS (fe/fo sets). Chunk t:
//   [lgkm0 | vmcnt(N) | barrier | fence | ds_read frags(t+1) | STAGE(t+4) |
//    16 MFMA on frags(t) (already in regs -> no LDS dependency)]
// ds_read + DMA latency hides under the ~520cyc MFMA block. lgkm0 at top is
// free in steady state (waits reads issued one full chunk earlier) and makes
// the buffer overwritten by STAGE(t+4) provably read-complete by ALL waves
// after the barrier (WAR-safe).

// stage chunk (bt2,kc2) into buffer bufp (4 x global_load_lds / thread)
#define STAGE(bt2, kc2, bufp)                                                  \
  do {                                                                         \
    _Pragma("unroll")                                                          \
    for (int it_ = 0; it_ < 4; ++it_) {                                        \
      __builtin_amdgcn_global_load_lds(                                        \
          (const __attribute__((address_space(1))) void*)(                     \
              Bm + (size_t)(colgbase + (bt2) * 128 + it_ * 32 + colL) * DDIM + \
              (kc2) * 64 + kelemL),                                            \
          (__attribute__((address_space(3))) void*)((bufp) + it_ * 4096 +      \
                                                    wave * 1024 + lane * 16),  \
          16, 0, 0);                                                           \
    }                                                                          \
  } while (0)

// B k-slice offset within a col's 128B, swizzle folded: ((s*2+hi)^(lane&7))<<4
#define XS(s) ((((s) * 2 + hi) ^ le7) << 4)

// read the 8 B fragments of one chunk into register set P (P##0A..P##3B)
#define READF(P, qbuf)                                                         \
  do {                                                                         \
    const char* rP_ = (qbuf) + bbase;                                          \
    P##0A = *(const bh8*)(rP_ + XS(0));                                        \
    P##0B = *(const bh8*)(rP_ + 4096 + XS(0));                                 \
    P##1A = *(const bh8*)(rP_ + XS(1));                                        \
    P##1B = *(const bh8*)(rP_ + 4096 + XS(1));                                 \
    P##2A = *(const bh8*)(rP_ + XS(2));                                        \
    P##2B = *(const bh8*)(rP_ + 4096 + XS(2));                                 \
    P##3A = *(const bh8*)(rP_ + XS(3));                                        \
    P##3B = *(const bh8*)(rP_ + 4096 + XS(3));                                 \
  } while (0)

#define MFMAS(kc, P)                                                           \
  do {                                                                         \
    acc00 = __builtin_amdgcn_mfma_f32_32x32x16_bf16(areg[0][(kc)*4+0], P##0A, acc00, 0,0,0); \
    acc01 = __builtin_amdgcn_mfma_f32_32x32x16_bf16(areg[0][(kc)*4+0], P##0B, acc01, 0,0,0); \
    acc10 = __builtin_amdgcn_mfma_f32_32x32x16_bf16(areg[1][(kc)*4+0], P##0A, acc10, 0,0,0); \
    acc11 = __builtin_amdgcn_mfma_f32_32x32x16_bf16(areg[1][(kc)*4+0], P##0B, acc11, 0,0,0); \
    acc00 = __builtin_amdgcn_mfma_f32_32x32x16_bf16(areg[0][(kc)*4+1], P##1A, acc00, 0,0,0); \
    acc01 = __builtin_amdgcn_mfma_f32_32x32x16_bf16(areg[0][(kc)*4+1], P##1B, acc01, 0,0,0); \
    acc10 = __builtin_amdgcn_mfma_f32_32x32x16_bf16(areg[1][(kc)*4+1], P##1A, acc10, 0,0,0); \
    acc11 = __builtin_amdgcn_mfma_f32_32x32x16_bf16(areg[1][(kc)*4+1], P##1B, acc11, 0,0,0); \
    acc00 = __builtin_amdgcn_mfma_f32_32x32x16_bf16(areg[0][(kc)*4+2], P##2A, acc00, 0,0,0); \
    acc01 = __builtin_amdgcn_mfma_f32_32x32x16_bf16(areg[0][(kc)*4+2], P##2B, acc01, 0,0,0); \
    acc10 = __builtin_amdgcn_mfma_f32_32x32x16_bf16(areg[1][(kc)*4+2], P##2A, acc10, 0,0,0); \
    acc11 = __builtin_amdgcn_mfma_f32_32x32x16_bf16(areg[1][(kc)*4+2], P##2B, acc11, 0,0,0); \
    acc00 = __builtin_amdgcn_mfma_f32_32x32x16_bf16(areg[0][(kc)*4+3], P##3A, acc00, 0,0,0); \
    acc01 = __builtin_amdgcn_mfma_f32_32x32x16_bf16(areg[0][(kc)*4+3], P##3B, acc01, 0,0,0); \
    acc10 = __builtin_amdgcn_mfma_f32_32x32x16_bf16(areg[1][(kc)*4+3], P##3A, acc10, 0,0,0); \
    acc11 = __builtin_amdgcn_mfma_f32_32x32x16_bf16(areg[1][(kc)*4+3], P##3B, acc11, 0,0,0); \
  } while (0)

// one chunk position. CUR: frag set consumed by MFMA (chunk t, k-page kc).
// NXT: frag set filled from qn (chunk t+1). Optionally stage chunk t+4.
#define CHUNKP(kc, CUR, NXT, qn, VM, DO_RD, DO_ST, SBT, SKC, sq)               \
  do {                                                                         \
    asm volatile("s_waitcnt lgkmcnt(0)" ::: "memory");                         \
    asm volatile("s_waitcnt vmcnt(%0)" ::"i"(VM) : "memory");                  \
    __builtin_amdgcn_s_barrier();                                              \
    asm volatile("" ::: "memory"); /* no LDS reads above the barrier */        \
    if (DO_RD) READF(NXT, qn);                                                 \
    if (DO_ST) STAGE(SBT, SKC, sq);                                            \
    MFMAS(kc, CUR);                                                            \
  } while (0)

// per-tile epilogue for one 32x32 acc; C layout (m74/m101):
// col = lane&31, row = (reg&3) + 8*(reg>>2) + 4*(lane>>5)
#define EPI32(A_, m_, n_)                                                      \
  do {                                                                         \
    fx16 v_ = A_;                                                              \
    A_ = fzero16();                                                            \
    _Pragma("unroll")                                                          \
    for (int g_ = 0; g_ < 16; g_ += 4) {                                       \
      e0 += fexp2(k1 * v_[g_ + 0]);                                            \
      e1 += fexp2(k1 * v_[g_ + 1]);                                            \
      e2 += fexp2(k1 * v_[g_ + 2]);                                            \
      e3 += fexp2(k1 * v_[g_ + 3]);                                            \
    }                                                                          \
    if (dtile) { /* block-uniform: at most 1 of 32 tiles */                    \
      const int gcol_ = colbase + wc * 64 + (n_) * 32 + (lane & 31);           \
      const int grow0_ = rowbase + wr * 64 + (m_) * 32 + 4 * hi;               \
      _Pragma("unroll")                                                        \
      for (int r_ = 0; r_ < 16; ++r_) {                                        \
        int grow_ = grow0_ + (r_ & 3) + 8 * (r_ >> 2);                         \
        if (grow_ == gcol_) {                                                  \
          d += softplus_f(-fmaf(scale, v_[r_], bias));                         \
          e0 -= fexp2(k1 * v_[r_]);                                            \
        }                                                                      \
      }                                                                        \
    }                                                                          \
  } while (0)

#define EPILOGUE(btv)                                                          \
  do {                                                                         \
    const int colbase = colgbase + (btv) * 128;                                \
    const bool dtile = (colbase == rowbase);                                   \
    EPI32(acc00, 0, 0); EPI32(acc01, 0, 1);                                    \
    EPI32(acc10, 1, 0); EPI32(acc11, 1, 1);                                    \
  } while (0)

__global__ __launch_bounds__(256, 2) void siglip_strip(
    const unsigned short* __restrict__ Am, const unsigned short* __restrict__ Bm,
    const float* __restrict__ scale_p, const float* __restrict__ bias_p,
    float* __restrict__ out) {
  __shared__ char lds[65536];    // B ring: 4 x 16KB
  char* q0 = lds;
  char* q1 = lds + 16384;
  char* q2 = lds + 32768;
  char* q3 = lds + 49152;

  const int tid  = threadIdx.x;
  const int lane = tid & 63;
  const int wave = tid >> 6;     // 0..3
  const int wr   = wave >> 1;    // 0..1
  const int wc   = wave & 1;     // 0..1
  // XCD-aware mapping: cg fixed per XCD (bid&7 = XCD on dispatch).
  const int bid  = blockIdx.x;
  const int rp   = ((bid >> 3) << 1) | (bid & 1);  // 0..127
  const int cg   = (bid >> 1) & 3;                 // 0..3
  const int rowbase  = rp * 128;
  const int colgbase = cg * 4096;

  // ---- per-lane constants ----
  const int hi  = lane >> 5;          // 0/1
  const int le7 = lane & 7;
  // staging: linear dest slot l*16 holds content (l*16) ^ ((l>>3)&7)<<4
  const int colL   = wave * 8 + (lane >> 3);                       // 0..31
  const int kelemL = (((lane & 7) * 16) ^ (((lane >> 3) & 7) << 4)) >> 1;
  // read base: col = wc*64 + n*32 + (lane&31), col stride 128B
  const int bbase = (wc * 64 + (lane & 31)) * 128;

  const float scale = *scale_p;   // uniform -> SGPR (lgkm domain)
  const float bias  = *bias_p;
  const float k1 = scale * LOG2E;
  const float eb = fexp2(bias * LOG2E);  // e^bias

  // ---- prologue: A slice into registers (32 x 16B loads, static indices) --
  bh8 areg[2][16];
  {
    const unsigned short* Aw = Am + (size_t)(rowbase + wr * 64) * DDIM;
#pragma unroll
    for (int m = 0; m < 2; ++m)
#pragma unroll
      for (int ks = 0; ks < 16; ++ks)
        areg[m][ks] = *(const bh8*)(Aw + (size_t)(m * 32 + (lane & 31)) * DDIM +
                                    ks * 16 + hi * 8);
  }
  // drain all prologue vmem so counted vmcnt below sees only staging loads
  asm volatile("s_waitcnt vmcnt(0)" ::: "memory");

  STAGE(0, 0, q0);  // chunk 0
  STAGE(0, 1, q1);  // chunk 1
  STAGE(0, 2, q2);  // chunk 2
  STAGE(0, 3, q3);  // chunk 3

  fx16 acc00 = fzero16(), acc01 = fzero16();
  fx16 acc10 = fzero16(), acc11 = fzero16();
  float e0 = 0.f, e1 = 0.f, e2 = 0.f, e3 = 0.f, d = 0.f;

  // B fragment register sets (even/odd chunks)
  bh8 fe0A, fe0B, fe1A, fe1B, fe2A, fe2B, fe3A, fe3B;
  bh8 fo0A, fo0B, fo1A, fo1B, fo2A, fo2B, fo3A, fo3B;

  // chunk 0 landed (leave 3 stages = 12 ops in flight); pre-read frags(0)
  asm volatile("s_waitcnt vmcnt(12)" ::: "memory");
  __builtin_amdgcn_s_barrier();
  asm volatile("" ::: "memory");
  READF(fe, q0);

  for (int bt = 0; bt < 31; ++bt) {
    CHUNKP(0, fe, fo, q1, 8, 1, 1, bt + 1, 0, q0);  // t=4bt+0
    CHUNKP(1, fo, fe, q2, 8, 1, 1, bt + 1, 1, q1);  // t=4bt+1
    CHUNKP(2, fe, fo, q3, 8, 1, 1, bt + 1, 2, q2);  // t=4bt+2
    CHUNKP(3, fo, fe, q0, 8, 1, 1, bt + 1, 3, q3);  // t=4bt+3
    EPILOGUE(bt);  // register-only; overlaps in-flight DMA
  }
  // ---- peeled bt = 31 (chunks 124..127; no further staging) ----
  CHUNKP(0, fe, fo, q1, 8, 1, 0, 0, 0, q0);  // t=124, read frags(125)
  CHUNKP(1, fo, fe, q2, 4, 1, 0, 0, 0, q0);  // t=125, read frags(126)
  CHUNKP(2, fe, fo, q3, 0, 1, 0, 0, 0, q0);  // t=126, read frags(127)
  MFMAS(3, fo);                              // t=127 (frags already in regs)
  EPILOGUE(31);

  float local = fmaf((e0 + e1) + (e2 + e3), eb, d);
#pragma unroll
  for (int off = 32; off > 0; off >>= 1) local += __shfl_xor(local, off, 64);

  __syncthreads();  // LDS reuse for block reduction
  float* red = (float*)lds;
  if (lane == 0) red[wave] = local;
  __syncthreads();
  if (tid == 0)
    atomicAdd(out, ((red[0] + red[1]) + (red[2] + red[3])) * (1.0f / 16384.0f));
}

// ===================== fallback: f32 inputs, reg-staged (no ws needed) =====
__device__ __forceinline__ unsigned swz256(unsigned o) {
  return o ^ (((o >> 8) & 7u) << 4);
}

__device__ __forceinline__ void map_tile(int bid, int& tr, int& tc) {
  int xcd = bid & 7;
  int idx = bid >> 3;
  int g   = idx >> 7;
  int w   = idx & 127;
  tr = xcd * 16 + (w >> 3);
  tc = g * 8 + (w & 7);
}

__global__ __launch_bounds__(256, 2) void siglip_fallback(
    const float* __restrict__ A, const float* __restrict__ B,
    const float* __restrict__ scale_p, const float* __restrict__ bias_p,
    float* __restrict__ out) {
  __shared__ char lds[65536];
  char* ldsA = lds;
  char* ldsB = lds + 32768;
  const int tid  = threadIdx.x;
  const int lane = tid & 63;
  const int wave = tid >> 6;
  const int wr   = wave >> 1;
  const int wc   = wave & 1;
  int tr, tc;
  map_tile(blockIdx.x, tr, tc);
  const int brow = tr * 128, bcol = tc * 128;

  fx4 acc[4][4];
#pragma unroll
  for (int m = 0; m < 4; ++m)
#pragma unroll
    for (int n = 0; n < 4; ++n) acc[m][n] = (fx4){0.f, 0.f, 0.f, 0.f};

#pragma unroll
  for (int p = 0; p < 2; ++p) {
    __syncthreads();
    const float* Af = A + (size_t)brow * DDIM + p * 128;
    const float* Bf = B + (size_t)bcol * DDIM + p * 128;
#pragma unroll
    for (int it = 0; it < 16; ++it) {
      int c = it * 256 + tid;
      int row = c >> 5, j = c & 31;
      unsigned o = row * 256 + j * 8;
      {
        float4 v = *(const float4*)(Af + (size_t)row * DDIM + j * 4);
        bh4 h;
        h[0] = f2bf(v.x); h[1] = f2bf(v.y); h[2] = f2bf(v.z); h[3] = f2bf(v.w);
        *(bh4*)(ldsA + swz256(o)) = h;
      }
      {
        float4 v = *(const float4*)(Bf + (size_t)row * DDIM + j * 4);
        bh4 h;
        h[0] = f2bf(v.x); h[1] = f2bf(v.y); h[2] = f2bf(v.z); h[3] = f2bf(v.w);
        *(bh4*)(ldsB + swz256(o)) = h;
      }
    }
    __syncthreads();
#pragma unroll
    for (int kk = 0; kk < 4; ++kk) {
      const int colb = kk * 64 + (lane >> 4) * 16;
      bh8 a[4], b[4];
#pragma unroll
      for (int m = 0; m < 4; ++m) {
        int r = wr * 64 + m * 16 + (lane & 15);
        a[m] = *(const bh8*)(ldsA + swz256((unsigned)(r * 256 + colb)));
      }
#pragma unroll
      for (int n = 0; n < 4; ++n) {
        int r = wc * 64 + n * 16 + (lane & 15);
        b[n] = *(const bh8*)(ldsB + swz256((unsigned)(r * 256 + colb)));
      }
#pragma unroll
      for (int m = 0; m < 4; ++m)
#pragma unroll
        for (int n = 0; n < 4; ++n)
          acc[m][n] = __builtin_amdgcn_mfma_f32_16x16x32_bf16(a[m], b[n],
                                                              acc[m][n], 0, 0, 0);
    }
  }

  const float scale = *scale_p;
  const float bias  = *bias_p;
  const float k1 = scale * LOG2E;
  const float k0 = bias * LOG2E;
  float s0 = 0.f, s1 = 0.f, s2 = 0.f, s3 = 0.f;
  const int  row0 = brow + wr * 64 + (lane >> 4) * 4;
  const int  col0 = bcol + wc * 64 + (lane & 15);
  const bool isdiag = (tr == tc);
#pragma unroll
  for (int m = 0; m < 4; ++m) {
#pragma unroll
    for (int n = 0; n < 4; ++n) {
      fx4 v = acc[m][n];
      s0 += fexp2(fmaf(k1, v[0], k0));
      s1 += fexp2(fmaf(k1, v[1], k0));
      s2 += fexp2(fmaf(k1, v[2], k0));
      s3 += fexp2(fmaf(k1, v[3], k0));
      if (isdiag) {
        const int gj = col0 + n * 16;
#pragma unroll
        for (int j = 0; j < 4; ++j) {
          const int gi = row0 + m * 16 + j;
          if (gi == gj) {
            float logit = fmaf(scale, v[j], bias);
            s0 += softplus_f(-logit) - fexp2(fmaf(k1, v[j], k0));
          }
        }
      }
    }
  }
  float local = (s0 + s1) + (s2 + s3);
#pragma unroll
  for (int off = 32; off > 0; off >>= 1) local += __shfl_xor(local, off, 64);

  __syncthreads();
  float* red = (float*)lds;
  if (lane == 0) red[wave] = local;
  __syncthreads();
  if (tid == 0)
    atomicAdd(out, (red[0] + red[1] + red[2] + red[3]) * (1.0f / 16384.0f));
}

extern "C" void kernel_launch(void* const* d_in, const int* in_sizes, int n_in,
                              void* d_out, int out_size, void* d_ws,
                              size_t ws_size, hipStream_t stream) {
  const float* img     = (const float*)d_in[0];
  const float* txt     = (const float*)d_in[1];
  const float* scale_p = (const float*)d_in[2];
  const float* bias_p  = (const float*)d_in[3];
  float* out = (float*)d_out;

  hipMemsetAsync(d_out, 0, (size_t)out_size * sizeof(float), stream);

  const size_t elems = (size_t)NROWS * DDIM;
  const size_t need  = 2 * elems * sizeof(unsigned short);  // 16.8 MB

  if (ws_size >= need) {
    unsigned short* Abf = (unsigned short*)d_ws;
    unsigned short* Bbf = Abf + elems;
    const int cast_blocks = (int)(elems / (256 * 8));  // 2048
    cast_bf16_kernel<<<cast_blocks, 256, 0, stream>>>(img, Abf);
    cast_bf16_kernel<<<cast_blocks, 256, 0, stream>>>(txt, Bbf);
    siglip_strip<<<512, 256, 0, stream>>>(Abf, Bbf, scale_p, bias_p, out);
    return;
  }
  const int nblocks = (NROWS / 128) * (NROWS / 128);  // 16384
  siglip_fallback<<<nblocks, 256, 0, stream>>>(img, txt, scale_p, bias_p, out);
}